// Round 12
// baseline (282.276 us; speedup 1.0000x reference)
//
#include <hip/hip_runtime.h>
#include <math.h>

#define CH 128
#define CAP 64     // bucket capacity; degrees Poisson(16), P(deg>64) ~ 3e-22
#define RB 13      // scatter range bits: 8192 ids/pass -> ~2MB active col/pass
#define NCHUNK 4   // channel chunks of 32: 50000*32*2B = 3.2MB < 4MB L2/XCD

typedef __attribute__((ext_vector_type(8))) short bf16x8;
typedef __attribute__((ext_vector_type(4))) float f32x4;

__device__ __forceinline__ unsigned short f2bf(float f) {
    union { float f; unsigned u; } v; v.f = f;
    unsigned r = v.u + 0x7FFF + ((v.u >> 16) & 1);   // round-to-nearest-even
    return (unsigned short)(r >> 16);
}
__device__ __forceinline__ float bflo(unsigned u) {
    union { unsigned u; float f; } v; v.u = u << 16; return v.f;
}
__device__ __forceinline__ float bfhi(unsigned u) {
    union { unsigned u; float f; } v; v.u = u & 0xFFFF0000u; return v.f;
}
__device__ __forceinline__ unsigned pack2bf(float a, float b) {
    return (unsigned)f2bf(a) | ((unsigned)f2bf(b) << 16);
}

// ---------------------------------------------------------------------------
// Kernel 1 (mega-fused, block-specialized) [R11-proven]:
//   blocks [0, SB): range-phased bucket scatter
//   blocks [SB, ..): gemm + attention + casts; xl written CHUNK-MAJOR bf16:
//     xl[chunk][node][32ch], chunk = channel>>5
// ---------------------------------------------------------------------------
__global__ __launch_bounds__(256) void fused_main(const float* __restrict__ x,
                                                  const float* __restrict__ attn_w,
                                                  const float* __restrict__ attn_b,
                                                  const float* __restrict__ lw,
                                                  unsigned short* __restrict__ xl,
                                                  float* __restrict__ w,
                                                  int nStrips, int N,
                                                  const int* __restrict__ nidx,
                                                  const int* __restrict__ eidx,
                                                  int* __restrict__ cntE,
                                                  unsigned short* __restrict__ colE,
                                                  int* __restrict__ cntN,
                                                  unsigned short* __restrict__ colN,
                                                  int nnz2, int npass, int SB) {
    __shared__ unsigned short wl[128 * 136];
    __shared__ float awl[128];
    if ((int)blockIdx.x < SB) {
        // ---- range-phased scatter (identical semantics to R10/R11) ----
        int k = blockIdx.x * 256 + threadIdx.x;
        if (k >= nnz2) return;
        int2 nv = ((const int2*)nidx)[k];
        int2 ev = ((const int2*)eidx)[k];
        int re0 = ev.x >> RB, re1 = ev.y >> RB;
        int rn0 = nv.x >> RB, rn1 = nv.y >> RB;
        for (int p = 0; p < npass; ++p) {
            if (re0 == p) {
                int r = atomicAdd(&cntE[ev.x], 1);
                colE[(size_t)ev.x * CAP + min(r, CAP - 1)] = (unsigned short)nv.x;
            }
            if (re1 == p) {
                int r = atomicAdd(&cntE[ev.y], 1);
                colE[(size_t)ev.y * CAP + min(r, CAP - 1)] = (unsigned short)nv.y;
            }
            if (rn0 == p) {
                int r = atomicAdd(&cntN[nv.x], 1);
                colN[(size_t)nv.x * CAP + min(r, CAP - 1)] = (unsigned short)ev.x;
            }
            if (rn1 == p) {
                int r = atomicAdd(&cntN[nv.y], 1);
                colN[(size_t)nv.y * CAP + min(r, CAP - 1)] = (unsigned short)ev.y;
            }
        }
        return;
    }
    // ---- gemm + attention part ----
    int tid = threadIdx.x;
    for (int i = tid; i < 2048; i += 256) {          // i = 8-element group
        float4 vlo = ((const float4*)lw)[2 * i];
        float4 vhi = ((const float4*)lw)[2 * i + 1];
        int4 dst;
        dst.x = (int)pack2bf(vlo.x, vlo.y);
        dst.y = (int)pack2bf(vlo.z, vlo.w);
        dst.z = (int)pack2bf(vhi.x, vhi.y);
        dst.w = (int)pack2bf(vhi.z, vhi.w);
        *(int4*)(wl + (i >> 4) * 136 + (i & 15) * 8) = dst;
    }
    if (tid < 128) awl[tid] = attn_w[tid];
    float ab = attn_b[0];
    __syncthreads();
    int gb = blockIdx.x - SB;
    int wid = (gb << 2) | (tid >> 6);
    int lane = tid & 63;
    int m = lane & 15, quad = lane >> 4;
    int nWaves = ((int)gridDim.x - SB) << 2;
    size_t N32 = (size_t)N * 32;
    for (int s = wid; s < nStrips; s += nWaves) {
        int r0 = s << 4;
        const float* xr = x + (size_t)(r0 + m) * CH + quad * 8;
        float att = 0.f;
        bf16x8 a0, a1, a2, a3;
#define LOAD_FRAG(AFRAG, F)                                                   \
        {                                                                     \
            float4 lo = *(const float4*)(xr + (F) * 32);                      \
            float4 hi = *(const float4*)(xr + (F) * 32 + 4);                  \
            const float* ap = &awl[(F) * 32 + quad * 8];                      \
            att += lo.x * ap[0] + lo.y * ap[1] + lo.z * ap[2] + lo.w * ap[3]  \
                 + hi.x * ap[4] + hi.y * ap[5] + hi.z * ap[6] + hi.w * ap[7]; \
            union { int4 i; bf16x8 v; } pk;                                   \
            pk.i.x = (int)pack2bf(lo.x, lo.y);                                \
            pk.i.y = (int)pack2bf(lo.z, lo.w);                                \
            pk.i.z = (int)pack2bf(hi.x, hi.y);                                \
            pk.i.w = (int)pack2bf(hi.z, hi.w);                                \
            AFRAG = pk.v;                                                     \
        }
        LOAD_FRAG(a0, 0)
        LOAD_FRAG(a1, 1)
        LOAD_FRAG(a2, 2)
        LOAD_FRAG(a3, 3)
#undef LOAD_FRAG
        att += __shfl_xor(att, 16, 64);
        att += __shfl_xor(att, 32, 64);
        if (quad == 0) w[r0 + m] = 1.0f / (1.0f + expf(-(att + ab)));
#pragma unroll
        for (int c0 = 0; c0 < 128; c0 += 16) {
            const unsigned short* wr = wl + (c0 + m) * 136 + quad * 8;
            f32x4 acc = {0.f, 0.f, 0.f, 0.f};
            acc = __builtin_amdgcn_mfma_f32_16x16x32_bf16(a0, *(const bf16x8*)(wr), acc, 0, 0, 0);
            acc = __builtin_amdgcn_mfma_f32_16x16x32_bf16(a1, *(const bf16x8*)(wr + 32), acc, 0, 0, 0);
            acc = __builtin_amdgcn_mfma_f32_16x16x32_bf16(a2, *(const bf16x8*)(wr + 64), acc, 0, 0, 0);
            acc = __builtin_amdgcn_mfma_f32_16x16x32_bf16(a3, *(const bf16x8*)(wr + 96), acc, 0, 0, 0);
            // node = r0+quad*4+reg, channel = c0+m  ->  chunk-major store
            unsigned short* oc = xl + (size_t)(c0 >> 5) * N32
                                    + (size_t)(r0 + quad * 4) * 32 + (c0 & 16) + m;
            oc[0]  = f2bf(acc[0]);
            oc[32] = f2bf(acc[1]);
            oc[64] = f2bf(acc[2]);
            oc[96] = f2bf(acc[3]);
        }
    }
}

// ---------------------------------------------------------------------------
// Kernel 2: edge pull, one channel-chunk per launch.
// 16 lanes per edge (2 ch per lane), 4 edges per wave. Gather working set =
// 3.2MB -> L2-resident per XCD.
// ---------------------------------------------------------------------------
__global__ __launch_bounds__(256) void edge_pull_c(const int* __restrict__ cntE,
                                                   const unsigned short* __restrict__ colE,
                                                   const unsigned short* __restrict__ xl,
                                                   unsigned short* __restrict__ ef,
                                                   int M, int N, int chunk) {
    int t = blockIdx.x * 256 + threadIdx.x;
    int e = t >> 4;
    if (e >= M) return;
    int sl = t & 15;
    int deg = cntE[e];
    const unsigned short* col = colE + (size_t)e * CAP;
    const unsigned short* xc = xl + (size_t)chunk * N * 32 + 2 * sl;
    float2 a0 = {0.f, 0.f}, a1 = {0.f, 0.f}, a2 = {0.f, 0.f}, a3 = {0.f, 0.f};
    int j = 0;
    for (; j + 3 < deg; j += 4) {
        int v0 = col[j], v1 = col[j + 1], v2 = col[j + 2], v3 = col[j + 3];
        unsigned u0 = *(const unsigned*)(xc + (size_t)v0 * 32);
        unsigned u1 = *(const unsigned*)(xc + (size_t)v1 * 32);
        unsigned u2 = *(const unsigned*)(xc + (size_t)v2 * 32);
        unsigned u3 = *(const unsigned*)(xc + (size_t)v3 * 32);
        a0.x += bflo(u0); a0.y += bfhi(u0);
        a1.x += bflo(u1); a1.y += bfhi(u1);
        a2.x += bflo(u2); a2.y += bfhi(u2);
        a3.x += bflo(u3); a3.y += bfhi(u3);
    }
    for (; j < deg; ++j) {
        unsigned u0 = *(const unsigned*)(xc + (size_t)col[j] * 32);
        a0.x += bflo(u0); a0.y += bfhi(u0);
    }
    a0.x += a1.x + a2.x + a3.x;
    a0.y += a1.y + a2.y + a3.y;
    float binv = deg > 0 ? 1.0f / (float)deg : 0.0f;
    *(unsigned*)(ef + (size_t)chunk * N * 32 + (size_t)e * 32 + 2 * sl) =
        pack2bf(a0.x * binv, a0.y * binv);
}

// ---------------------------------------------------------------------------
// Kernel 3: node pull, one channel-chunk per launch. chunk 0 computes
// dinv[v] = 1/sum(w[e]) (f32 exact) and caches it; chunks 1-3 reuse.
// ---------------------------------------------------------------------------
__global__ __launch_bounds__(256) void node_pull_c(const int* __restrict__ cntN,
                                                   const unsigned short* __restrict__ colN,
                                                   const unsigned short* __restrict__ ef,
                                                   const float* __restrict__ w,
                                                   float* __restrict__ dinvA,
                                                   const float* __restrict__ bias,
                                                   float* __restrict__ out,
                                                   int N, int chunk) {
    int t = blockIdx.x * 256 + threadIdx.x;
    int v = t >> 4;
    if (v >= N) return;
    int sl = t & 15;
    int deg = cntN[v];
    const unsigned short* col = colN + (size_t)v * CAP;
    const unsigned short* ec = ef + (size_t)chunk * N * 32 + 2 * sl;
    float2 a0 = {0.f, 0.f}, a1 = {0.f, 0.f}, a2 = {0.f, 0.f}, a3 = {0.f, 0.f};
    float ds = 0.f;
    int j = 0;
    for (; j + 3 < deg; j += 4) {
        int e0 = col[j], e1 = col[j + 1], e2 = col[j + 2], e3 = col[j + 3];
        unsigned u0 = *(const unsigned*)(ec + (size_t)e0 * 32);
        unsigned u1 = *(const unsigned*)(ec + (size_t)e1 * 32);
        unsigned u2 = *(const unsigned*)(ec + (size_t)e2 * 32);
        unsigned u3 = *(const unsigned*)(ec + (size_t)e3 * 32);
        if (chunk == 0) ds += w[e0] + w[e1] + w[e2] + w[e3];
        a0.x += bflo(u0); a0.y += bfhi(u0);
        a1.x += bflo(u1); a1.y += bfhi(u1);
        a2.x += bflo(u2); a2.y += bfhi(u2);
        a3.x += bflo(u3); a3.y += bfhi(u3);
    }
    for (; j < deg; ++j) {
        int e0 = col[j];
        unsigned u0 = *(const unsigned*)(ec + (size_t)e0 * 32);
        if (chunk == 0) ds += w[e0];
        a0.x += bflo(u0); a0.y += bfhi(u0);
    }
    a0.x += a1.x + a2.x + a3.x;
    a0.y += a1.y + a2.y + a3.y;
    float dinv;
    if (chunk == 0) {
        dinv = ds > 0.f ? 1.0f / ds : 0.0f;
        if (sl == 0) dinvA[v] = dinv;
    } else {
        dinv = dinvA[v];
    }
    float2 bi = *(const float2*)(bias + chunk * 32 + 2 * sl);
    float2 o = {a0.x * dinv + bi.x, a0.y * dinv + bi.y};
    *(float2*)(out + (size_t)v * CH + chunk * 32 + 2 * sl) = o;
}

extern "C" void kernel_launch(void* const* d_in, const int* in_sizes, int n_in,
                              void* d_out, int out_size, void* d_ws, size_t ws_size,
                              hipStream_t stream) {
    const float* x      = (const float*)d_in[0];
    const int*   hei    = (const int*)d_in[1];
    const float* attn_w = (const float*)d_in[2];
    const float* attn_b = (const float*)d_in[3];
    const float* lin_w  = (const float*)d_in[4];
    const float* bias   = (const float*)d_in[5];
    float* out = (float*)d_out;

    const int N   = in_sizes[0] / CH;   // 50000 (== M here)
    const int nnz = in_sizes[1] / 2;    // 800000 (even)
    const int* nidx = hei;              // row 0: node ids
    const int* eidx = hei + nnz;        // row 1: hyperedge ids

    // workspace layout
    unsigned short* S    = (unsigned short*)d_ws;          // N*CH ushorts (efbf chunk-major)
    float*          w    = (float*)(S + (size_t)N * CH);   // N floats
    float*          dinv = w + N;                          // N floats
    int*            cntE = (int*)(dinv + N);               // N   } contiguous
    int*            cntN = cntE + N;                       // N   } for memset
    unsigned short* colE = (unsigned short*)(cntN + N);    // N*CAP ushorts
    unsigned short* colN = colE + (size_t)N * CAP;         // N*CAP ushorts

    unsigned short* efbf = S;
    unsigned short* xlbf = (unsigned short*)out;   // bf16 xl (chunk-major) in d_out

    hipMemsetAsync(cntE, 0, (size_t)2 * N * sizeof(int), stream);

    int nnz2 = nnz / 2;                    // 400000
    int SB = (nnz2 + 255) / 256;           // 1563 scatter blocks
    int nStrips = N / 16;                  // 3125
    int GB = (nStrips + 3) / 4;            // 782 gemm blocks
    int npass = ((N - 1) >> RB) + 1;       // 7 ranges of 8192 ids
    fused_main<<<SB + GB, 256, 0, stream>>>(x, attn_w, attn_b, lin_w, xlbf, w,
                                            nStrips, N, nidx, eidx, cntE, colE,
                                            cntN, colN, nnz2, npass, SB);

    int PB = (N * 16 + 255) / 256;         // 3125 blocks per chunk
    for (int c = 0; c < NCHUNK; ++c)
        edge_pull_c<<<PB, 256, 0, stream>>>(cntE, colE, xlbf, efbf, N, N, c);
    for (int c = 0; c < NCHUNK; ++c)
        node_pull_c<<<PB, 256, 0, stream>>>(cntN, colN, efbf, w, dinv, bias, out, N, c);
}

// Round 13
// 261.574 us; speedup vs baseline: 1.0791x; 1.0791x over previous
//
#include <hip/hip_runtime.h>
#include <math.h>

#define CH 128
#define CAP 64     // bucket capacity; degrees Poisson(16), P(deg>64) ~ 3e-22
#define RB 13      // scatter range bits: 8192 ids/pass -> ~2MB active col/pass

typedef __attribute__((ext_vector_type(8))) short bf16x8;
typedef __attribute__((ext_vector_type(4))) float f32x4;

__device__ __forceinline__ unsigned short f2bf(float f) {
    union { float f; unsigned u; } v; v.f = f;
    unsigned r = v.u + 0x7FFF + ((v.u >> 16) & 1);   // round-to-nearest-even
    return (unsigned short)(r >> 16);
}
__device__ __forceinline__ float bflo(unsigned u) {
    union { unsigned u; float f; } v; v.u = u << 16; return v.f;
}
__device__ __forceinline__ float bfhi(unsigned u) {
    union { unsigned u; float f; } v; v.u = u & 0xFFFF0000u; return v.f;
}
__device__ __forceinline__ unsigned pack2bf(float a, float b) {
    return (unsigned)f2bf(a) | ((unsigned)f2bf(b) << 16);
}

// ---------------------------------------------------------------------------
// Kernel 1 (mega-fused, block-specialized) [R11-proven, unchanged]:
//   blocks [0, SB): range-phased bucket scatter
//   blocks [SB, ..): gemm + attention + casts; xl row-major bf16 in d_out
// ---------------------------------------------------------------------------
__global__ __launch_bounds__(256) void fused_main(const float* __restrict__ x,
                                                  const float* __restrict__ attn_w,
                                                  const float* __restrict__ attn_b,
                                                  const float* __restrict__ lw,
                                                  unsigned short* __restrict__ xl,
                                                  float* __restrict__ w,
                                                  int nStrips,
                                                  const int* __restrict__ nidx,
                                                  const int* __restrict__ eidx,
                                                  int* __restrict__ cntE,
                                                  unsigned short* __restrict__ colE,
                                                  int* __restrict__ cntN,
                                                  unsigned short* __restrict__ colN,
                                                  int nnz2, int npass, int SB) {
    __shared__ unsigned short wl[128 * 136];
    __shared__ float awl[128];
    if ((int)blockIdx.x < SB) {
        int k = blockIdx.x * 256 + threadIdx.x;
        if (k >= nnz2) return;
        int2 nv = ((const int2*)nidx)[k];
        int2 ev = ((const int2*)eidx)[k];
        int re0 = ev.x >> RB, re1 = ev.y >> RB;
        int rn0 = nv.x >> RB, rn1 = nv.y >> RB;
        for (int p = 0; p < npass; ++p) {
            if (re0 == p) {
                int r = atomicAdd(&cntE[ev.x], 1);
                colE[(size_t)ev.x * CAP + min(r, CAP - 1)] = (unsigned short)nv.x;
            }
            if (re1 == p) {
                int r = atomicAdd(&cntE[ev.y], 1);
                colE[(size_t)ev.y * CAP + min(r, CAP - 1)] = (unsigned short)nv.y;
            }
            if (rn0 == p) {
                int r = atomicAdd(&cntN[nv.x], 1);
                colN[(size_t)nv.x * CAP + min(r, CAP - 1)] = (unsigned short)ev.x;
            }
            if (rn1 == p) {
                int r = atomicAdd(&cntN[nv.y], 1);
                colN[(size_t)nv.y * CAP + min(r, CAP - 1)] = (unsigned short)ev.y;
            }
        }
        return;
    }
    int tid = threadIdx.x;
    for (int i = tid; i < 2048; i += 256) {          // i = 8-element group
        float4 vlo = ((const float4*)lw)[2 * i];
        float4 vhi = ((const float4*)lw)[2 * i + 1];
        int4 dst;
        dst.x = (int)pack2bf(vlo.x, vlo.y);
        dst.y = (int)pack2bf(vlo.z, vlo.w);
        dst.z = (int)pack2bf(vhi.x, vhi.y);
        dst.w = (int)pack2bf(vhi.z, vhi.w);
        *(int4*)(wl + (i >> 4) * 136 + (i & 15) * 8) = dst;
    }
    if (tid < 128) awl[tid] = attn_w[tid];
    float ab = attn_b[0];
    __syncthreads();
    int gb = blockIdx.x - SB;
    int wid = (gb << 2) | (tid >> 6);
    int lane = tid & 63;
    int m = lane & 15, quad = lane >> 4;
    int nWaves = ((int)gridDim.x - SB) << 2;
    for (int s = wid; s < nStrips; s += nWaves) {
        int r0 = s << 4;
        const float* xr = x + (size_t)(r0 + m) * CH + quad * 8;
        float att = 0.f;
        bf16x8 a0, a1, a2, a3;
#define LOAD_FRAG(AFRAG, F)                                                   \
        {                                                                     \
            float4 lo = *(const float4*)(xr + (F) * 32);                      \
            float4 hi = *(const float4*)(xr + (F) * 32 + 4);                  \
            const float* ap = &awl[(F) * 32 + quad * 8];                      \
            att += lo.x * ap[0] + lo.y * ap[1] + lo.z * ap[2] + lo.w * ap[3]  \
                 + hi.x * ap[4] + hi.y * ap[5] + hi.z * ap[6] + hi.w * ap[7]; \
            union { int4 i; bf16x8 v; } pk;                                   \
            pk.i.x = (int)pack2bf(lo.x, lo.y);                                \
            pk.i.y = (int)pack2bf(lo.z, lo.w);                                \
            pk.i.z = (int)pack2bf(hi.x, hi.y);                                \
            pk.i.w = (int)pack2bf(hi.z, hi.w);                                \
            AFRAG = pk.v;                                                     \
        }
        LOAD_FRAG(a0, 0)
        LOAD_FRAG(a1, 1)
        LOAD_FRAG(a2, 2)
        LOAD_FRAG(a3, 3)
#undef LOAD_FRAG
        att += __shfl_xor(att, 16, 64);
        att += __shfl_xor(att, 32, 64);
        if (quad == 0) w[r0 + m] = 1.0f / (1.0f + expf(-(att + ab)));
        unsigned short* orow = xl + (size_t)(r0 + quad * 4) * CH + m;
#pragma unroll
        for (int c0 = 0; c0 < 128; c0 += 16) {
            const unsigned short* wr = wl + (c0 + m) * 136 + quad * 8;
            f32x4 acc = {0.f, 0.f, 0.f, 0.f};
            acc = __builtin_amdgcn_mfma_f32_16x16x32_bf16(a0, *(const bf16x8*)(wr), acc, 0, 0, 0);
            acc = __builtin_amdgcn_mfma_f32_16x16x32_bf16(a1, *(const bf16x8*)(wr + 32), acc, 0, 0, 0);
            acc = __builtin_amdgcn_mfma_f32_16x16x32_bf16(a2, *(const bf16x8*)(wr + 64), acc, 0, 0, 0);
            acc = __builtin_amdgcn_mfma_f32_16x16x32_bf16(a3, *(const bf16x8*)(wr + 96), acc, 0, 0, 0);
            orow[c0]            = f2bf(acc[0]);
            orow[c0 + CH]       = f2bf(acc[1]);
            orow[c0 + 2 * CH]   = f2bf(acc[2]);
            orow[c0 + 3 * CH]   = f2bf(acc[3]);
        }
    }
}

// ---------------------------------------------------------------------------
// Kernel 2: edge pull, 16-way masked gather unroll (16 loads in flight/wave).
// col rows are CAP=64 entries, 128B-aligned: uint4 reads at j, j+8 always
// in-bounds; entries >= deg are garbage -> index clamped (memory-safe) and
// contribution dropped via select (NaN-safe).
// ---------------------------------------------------------------------------
__global__ __launch_bounds__(256) void edge_pull(const int* __restrict__ cntE,
                                                 const unsigned short* __restrict__ colE,
                                                 const unsigned short* __restrict__ xl,
                                                 unsigned short* __restrict__ ef,
                                                 int M, int Nm1) {
    int e = (blockIdx.x << 2) | (threadIdx.x >> 6);
    if (e >= M) return;
    int lane = threadIdx.x & 63;
    int deg = cntE[e];
    const unsigned short* col = colE + (size_t)e * CAP;
    float2 acc[8];
#pragma unroll
    for (int k = 0; k < 8; ++k) acc[k] = {0.f, 0.f};
    for (int j = 0; j < deg; j += 16) {
        uint4 c0 = *(const uint4*)(col + j);
        uint4 c1 = *(const uint4*)(col + j + 8);
        unsigned wd[8] = {c0.x, c0.y, c0.z, c0.w, c1.x, c1.y, c1.z, c1.w};
#pragma unroll
        for (int k = 0; k < 16; ++k) {
            int idx = (int)((wd[k >> 1] >> ((k & 1) * 16)) & 0xFFFFu);
            idx = min(idx, Nm1);
            unsigned u = *(const unsigned*)(xl + (size_t)idx * CH + 2 * lane);
            bool act = (j + k) < deg;
            acc[k & 7].x += act ? bflo(u) : 0.f;
            acc[k & 7].y += act ? bfhi(u) : 0.f;
        }
    }
    float2 a = {acc[0].x + acc[1].x + acc[2].x + acc[3].x +
                acc[4].x + acc[5].x + acc[6].x + acc[7].x,
                acc[0].y + acc[1].y + acc[2].y + acc[3].y +
                acc[4].y + acc[5].y + acc[6].y + acc[7].y};
    float binv = deg > 0 ? 1.0f / (float)deg : 0.0f;
    *(unsigned*)(ef + (size_t)e * CH + 2 * lane) = pack2bf(a.x * binv, a.y * binv);
}

// ---------------------------------------------------------------------------
// Kernel 3: node pull, same 16-way masked scheme; also gathers w[e] for
// D_v (f32 exact), then out = Dinv*sum + bias.
// ---------------------------------------------------------------------------
__global__ __launch_bounds__(256) void node_pull(const int* __restrict__ cntN,
                                                 const unsigned short* __restrict__ colN,
                                                 const unsigned short* __restrict__ ef,
                                                 const float* __restrict__ w,
                                                 const float* __restrict__ bias,
                                                 float* __restrict__ out,
                                                 int N, int Nm1) {
    int v = (blockIdx.x << 2) | (threadIdx.x >> 6);
    if (v >= N) return;
    int lane = threadIdx.x & 63;
    int deg = cntN[v];
    const unsigned short* col = colN + (size_t)v * CAP;
    float2 acc[8];
#pragma unroll
    for (int k = 0; k < 8; ++k) acc[k] = {0.f, 0.f};
    float ds = 0.f;
    for (int j = 0; j < deg; j += 16) {
        uint4 c0 = *(const uint4*)(col + j);
        uint4 c1 = *(const uint4*)(col + j + 8);
        unsigned wd[8] = {c0.x, c0.y, c0.z, c0.w, c1.x, c1.y, c1.z, c1.w};
#pragma unroll
        for (int k = 0; k < 16; ++k) {
            int idx = (int)((wd[k >> 1] >> ((k & 1) * 16)) & 0xFFFFu);
            idx = min(idx, Nm1);
            unsigned u = *(const unsigned*)(ef + (size_t)idx * CH + 2 * lane);
            float wv = w[idx];
            bool act = (j + k) < deg;
            acc[k & 7].x += act ? bflo(u) : 0.f;
            acc[k & 7].y += act ? bfhi(u) : 0.f;
            ds += act ? wv : 0.f;
        }
    }
    float2 a = {acc[0].x + acc[1].x + acc[2].x + acc[3].x +
                acc[4].x + acc[5].x + acc[6].x + acc[7].x,
                acc[0].y + acc[1].y + acc[2].y + acc[3].y +
                acc[4].y + acc[5].y + acc[6].y + acc[7].y};
    float dinv = ds > 0.f ? 1.0f / ds : 0.0f;
    float2 bi = *(const float2*)(bias + 2 * lane);
    float2 o = {a.x * dinv + bi.x, a.y * dinv + bi.y};
    *(float2*)(out + (size_t)v * CH + 2 * lane) = o;
}

extern "C" void kernel_launch(void* const* d_in, const int* in_sizes, int n_in,
                              void* d_out, int out_size, void* d_ws, size_t ws_size,
                              hipStream_t stream) {
    const float* x      = (const float*)d_in[0];
    const int*   hei    = (const int*)d_in[1];
    const float* attn_w = (const float*)d_in[2];
    const float* attn_b = (const float*)d_in[3];
    const float* lin_w  = (const float*)d_in[4];
    const float* bias   = (const float*)d_in[5];
    float* out = (float*)d_out;

    const int N   = in_sizes[0] / CH;   // 50000 (== M here)
    const int nnz = in_sizes[1] / 2;    // 800000 (even)
    const int* nidx = hei;              // row 0: node ids
    const int* eidx = hei + nnz;        // row 1: hyperedge ids

    // workspace layout [R11-proven]
    unsigned short* S    = (unsigned short*)d_ws;          // N*CH ushorts (efbf)
    float*          w    = (float*)(S + (size_t)N * CH);   // N floats
    int*            cntE = (int*)(w + N);                  // N   } contiguous
    int*            cntN = cntE + N;                       // N   } for memset
    unsigned short* colE = (unsigned short*)(cntN + N);    // N*CAP ushorts
    unsigned short* colN = colE + (size_t)N * CAP;         // N*CAP ushorts

    unsigned short* efbf = S;
    unsigned short* xlbf = (unsigned short*)out;   // bf16 xl in d_out

    hipMemsetAsync(cntE, 0, (size_t)2 * N * sizeof(int), stream);

    int nnz2 = nnz / 2;                    // 400000
    int SB = (nnz2 + 255) / 256;           // 1563 scatter blocks
    int nStrips = N / 16;                  // 3125
    int GB = (nStrips + 3) / 4;            // 782 gemm blocks
    int npass = ((N - 1) >> RB) + 1;       // 7 ranges of 8192 ids
    fused_main<<<SB + GB, 256, 0, stream>>>(x, attn_w, attn_b, lin_w, xlbf, w,
                                            nStrips, nidx, eidx, cntE, colE,
                                            cntN, colN, nnz2, npass, SB);

    edge_pull<<<(N + 3) / 4, 256, 0, stream>>>(cntE, colE, xlbf, efbf, N, N - 1);
    node_pull<<<(N + 3) / 4, 256, 0, stream>>>(cntN, colN, efbf, w, bias, out, N, N - 1);
}